// Round 7
// baseline (16315.849 us; speedup 1.0000x reference)
//
#include <hip/hip_runtime.h>

#define BB 128   // batch
#define SS 128   // seq
#define EE 256   // enc dim
#define DD 256   // lstm hidden
#define OO 64    // out dim

// bf16 weight buffer layout (ushort offsets) inside d_out scratch
#define W1_OFF   0         // 768*256   = 196608 (rows: Wh|Wc|We)
#define WHH_OFF  196608    // 256*1024  = 262144
#define WIH_OFF  458752    // 64*1024   = 65536
#define FCW_OFF  524288    // 320*64    = 20480
#define WTOTAL   544768

// Opaque-value pin: forbids remat-from-memory (value becomes asm output).
#define PIN4(v_) asm volatile("" : "+v"((v_).x), "+v"((v_).y), "+v"((v_).z), "+v"((v_).w))

__device__ __forceinline__ float fsig(float x) { return 1.0f / (1.0f + __expf(-x)); }
__device__ __forceinline__ float ftanh(float x) {
    float t = __expf(-2.0f * fabsf(x));
    float r = (1.0f - t) / (1.0f + t);
    return copysignf(r, x);
}
// swizzle within 32-float groups (rotation by 4*(group)): conflict-free strided access
__device__ __forceinline__ int SWZ(int e) { return (e & ~31) | ((e + 4 * (e >> 5)) & 31); }
__device__ __forceinline__ float bflo(unsigned int u) { return __uint_as_float(u << 16); }
__device__ __forceinline__ float bfhi(unsigned int u) { return __uint_as_float(u & 0xffff0000u); }

__device__ __forceinline__ void fma8(const uint4 w, const float xv, float* acc) {
    acc[0] += xv * bflo(w.x); acc[1] += xv * bfhi(w.x);
    acc[2] += xv * bflo(w.y); acc[3] += xv * bfhi(w.y);
    acc[4] += xv * bflo(w.z); acc[5] += xv * bfhi(w.z);
    acc[6] += xv * bflo(w.w); acc[7] += xv * bfhi(w.w);
}

// fp32 -> bf16 (RNE) weight conversion, runs every launch (graph-safe, same work)
__global__ __launch_bounds__(256) void conv_kernel(
    const float* __restrict__ W1, const float* __restrict__ Whh,
    const float* __restrict__ Wih, const float* __restrict__ fcW,
    unsigned short* __restrict__ out)
{
    const int idx = blockIdx.x * 256 + threadIdx.x;
    float f;
    if      (idx < WHH_OFF)  f = W1[idx];
    else if (idx < WIH_OFF)  f = Whh[idx - WHH_OFF];
    else if (idx < FCW_OFF)  f = Wih[idx - WIH_OFF];
    else if (idx < WTOTAL)   f = fcW[idx - FCW_OFF];
    else return;
    unsigned int u = __float_as_uint(f);
    u = (u + 0x7fffu + ((u >> 16) & 1u)) >> 16;
    out[idx] = (unsigned short)u;
}

// One block (1024 thr, 16 waves) per batch row; whole scan block-local.
// ALL weights live in per-thread registers (loaded once, pinned). inp in LDS.
// Zero per-step global weight traffic; per-phase reduces via in-wave shfl.
__global__ __launch_bounds__(1024, 4) void scan_kernel(
    const float* __restrict__ inp,   // B,S,E
    const float* __restrict__ yhist, // B,S,OO
    const float* __restrict__ h0, const float* __restrict__ c0,
    const float* __restrict__ W1f,   // fp32 W1 (only We rows used here, init)
    const float* __restrict__ b1, const float* __restrict__ w2, const float* __restrict__ b2,
    const float* __restrict__ bih, const float* __restrict__ bhh,
    const float* __restrict__ fcb,
    const unsigned short* __restrict__ wbf,  // bf16 weights (see *_OFF)
    float* __restrict__ hctxT)       // ws: [512][128] (0..255 h, 256..511 ctx)
{
    __shared__ float sh_inp[SS * EE];      // 131072 B  (P3 reads are conflict-free: lanes span e)
    __shared__ float red[16 * 256];        // 16384 B   shared scratch: We-stage / ctx / yt / gates
    __shared__ float sh_h[DD], sh_c[DD];   // 2048
    __shared__ float sh_hc[EE];            // 1024 (SWZ'd)
    __shared__ float sh_w2[EE];            // 1024 (SWZ'd)
    __shared__ float sh_ctx[EE];           // 1024
    __shared__ float sh_raw[SS];           // 512  exp(scores)
    __shared__ float sh_y[OO], sh_yt[OO];  // 512
    __shared__ float sh_misc[1];
    // total ~153.6 KB -> 1 block/CU (as before)

    const int b = blockIdx.x, t = threadIdx.x;
    const float* inp_b = inp + (size_t)b * SS * EE;
    const unsigned short* W1bf  = wbf + W1_OFF;
    const unsigned short* Whhbf = wbf + WHH_OFF;
    const unsigned short* Wihbf = wbf + WIH_OFF;
    const unsigned short* fcWbf = wbf + FCW_OFF;
    const float b2v = b2[0];

    const int wv = t >> 6, lane = t & 63;

    // role constants
    const int kg1 = lane >> 1, c1b = wv * 16 + (lane & 1) * 8;   // P1: 32 kg x 16k, 8 cols
    const int kgb = lane >> 3, cbb = wv * 64 + (lane & 7) * 8;   // P1b/P4: 8 kg, 8 cols
    const int s_own = t >> 3, a2 = t & 7, e0 = a2 * 32;          // P2 / enc_proj
    const int e4 = (t & 63) * 4, sc = t >> 6;                    // P3
    const int o4 = (t & 15) * 4, kc3 = t >> 4;                   // P3b

    // ---- load ALL weights into registers (once) and pin them ----
    uint4 w1r[16];                         // W1 rows kg1*16..+16, cols c1b..+8   (64 VGPR)
    #pragma unroll
    for (int i = 0; i < 16; ++i)
        w1r[i] = *(const uint4*)(W1bf + (size_t)(kg1 * 16 + i) * 256 + c1b);
    uint4 whr[32];                         // Whh rows kgb*32..+32, cols cbb..+8  (128 VGPR)
    #pragma unroll
    for (int i = 0; i < 32; ++i)
        whr[i] = *(const uint4*)(Whhbf + (size_t)(kgb * 32 + i) * 1024 + cbb);
    uint4 wir[8];                          // Wih rows kgb*8..+8, cols cbb..+8    (32 VGPR)
    #pragma unroll
    for (int i = 0; i < 8; ++i)
        wir[i] = *(const uint4*)(Wihbf + (size_t)(kgb * 8 + i) * 1024 + cbb);
    uint2 fwr[5];                          // fcW rows kc3*5..+5, cols o4..+4     (10 VGPR)
    #pragma unroll
    for (int i = 0; i < 5; ++i)
        fwr[i] = *(const uint2*)(fcWbf + (kc3 * 5 + i) * 64 + o4);
    #pragma unroll
    for (int i = 0; i < 16; ++i) PIN4(w1r[i]);
    #pragma unroll
    for (int i = 0; i < 32; ++i) PIN4(whr[i]);
    #pragma unroll
    for (int i = 0; i < 8; ++i)  PIN4(wir[i]);
    #pragma unroll
    for (int i = 0; i < 5; ++i)  asm volatile("" : "+v"(fwr[i].x), "+v"(fwr[i].y));

    // ---- stage inp -> LDS (fp32, plain stride 256) ----
    #pragma unroll
    for (int i = 0; i < 8; ++i) {
        const int idx = i * 1024 + t;
        const int s = idx >> 6, c4 = (idx & 63) * 4;
        *(float4*)&sh_inp[s * 256 + c4] = *(const float4*)(inp_b + (size_t)idx * 4);
    }
    if (t < 256) {
        sh_h[t] = h0[b * 256 + t]; sh_c[t] = c0[b * 256 + t];
        sh_w2[SWZ(t)] = w2[t];
    }
    float bs4[4] = {0.f, 0.f, 0.f, 0.f};
    if (t < 256) {
        #pragma unroll
        for (int q = 0; q < 4; ++q) bs4[q] = bih[q * 256 + t] + bhh[q * 256 + t];
    }
    const float fcb_reg = (t < 64) ? fcb[t] : 0.f;
    __syncthreads();

    // ---- enc_proj (+b1) into registers er[32], reading inp from LDS ----
    float er[32];
    #pragma unroll
    for (int j = 0; j < 32; ++j) er[j] = 0.f;
    {
        const float* We = W1f + 512 * 256;
        for (int kc = 0; kc < 16; ++kc) {
            {   // stage We rows [kc*16,+16) x 256 -> red
                const int row = t >> 6, c4 = (t & 63) * 4;
                *(float4*)&red[row * 256 + c4] =
                    *(const float4*)(We + (size_t)(kc * 16 + row) * 256 + c4);
            }
            __syncthreads();
            for (int k = 0; k < 16; ++k) {
                const float xv = sh_inp[s_own * 256 + kc * 16 + k];
                #pragma unroll
                for (int j4 = 0; j4 < 8; ++j4) {
                    float4 w = *(const float4*)&red[k * 256 + e0 + j4 * 4];
                    er[j4*4+0] += xv * w.x; er[j4*4+1] += xv * w.y;
                    er[j4*4+2] += xv * w.z; er[j4*4+3] += xv * w.w;
                }
            }
            __syncthreads();
        }
        if (t < 256) red[t] = b1[t];
        __syncthreads();
        #pragma unroll
        for (int j4 = 0; j4 < 8; ++j4) {
            float4 v = *(const float4*)&red[e0 + j4 * 4];
            er[j4*4+0] += v.x; er[j4*4+1] += v.y; er[j4*4+2] += v.z; er[j4*4+3] += v.w;
        }
        __syncthreads();
    }

    for (int ts = 0; ts < SS; ++ts) {
        if (t < 64) sh_y[t] = yhist[(size_t)b * SS * OO + ts * OO + t];

        // ---- P1: hc from register W1; in-wave butterfly over 32 kgroups
        {
            float acc[8];
            #pragma unroll
            for (int r = 0; r < 8; ++r) acc[r] = 0.f;
            const float* xsrc = (kg1 < 16) ? &sh_h[kg1 * 16] : &sh_c[kg1 * 16 - 256];
            #pragma unroll
            for (int i = 0; i < 16; ++i) fma8(w1r[i], xsrc[i], acc);
            #pragma unroll
            for (int m = 2; m <= 32; m <<= 1) {
                #pragma unroll
                for (int r = 0; r < 8; ++r) acc[r] += __shfl_xor(acc[r], m);
            }
            if (lane < 2) {
                *(float4*)&sh_hc[SWZ(c1b)]     = make_float4(acc[0], acc[1], acc[2], acc[3]);
                *(float4*)&sh_hc[SWZ(c1b + 4)] = make_float4(acc[4], acc[5], acc[6], acc[7]);
            }
        }
        // ---- P1b: g = Whh·h from register Whh (kept in regs until P4)
        float g[8];
        #pragma unroll
        for (int r = 0; r < 8; ++r) g[r] = 0.f;
        {
            const float* hsrc = &sh_h[kgb * 32];
            #pragma unroll
            for (int i = 0; i < 32; ++i) fma8(whr[i], hsrc[i], g);
        }
        __syncthreads();                                     // bar1

        // ---- P2: scores from er + swizzled hc/w2 (conflict-free)
        {
            float acc = 0.f;
            #pragma unroll
            for (int j4 = 0; j4 < 8; ++j4) {
                const int phys = e0 + ((j4 * 4 + 4 * a2) & 31);
                float4 hc4 = *(const float4*)&sh_hc[phys];
                float4 w24 = *(const float4*)&sh_w2[phys];
                acc += ftanh(er[j4*4+0] + hc4.x) * w24.x;
                acc += ftanh(er[j4*4+1] + hc4.y) * w24.y;
                acc += ftanh(er[j4*4+2] + hc4.z) * w24.z;
                acc += ftanh(er[j4*4+3] + hc4.w) * w24.w;
            }
            acc += __shfl_xor(acc, 1);
            acc += __shfl_xor(acc, 2);
            acc += __shfl_xor(acc, 4);
            if (a2 == 0) sh_raw[s_own] = __expf(acc + b2v);  // max-free: |score| <= sum|w2| ~ 10
        }
        __syncthreads();                                     // bar2
        if (t < 64) {
            float v = sh_raw[t] + sh_raw[t + 64];
            #pragma unroll
            for (int m = 32; m > 0; m >>= 1) v += __shfl_xor(v, m);
            if (t == 0) sh_misc[0] = 1.0f / v;
        }
        __syncthreads();                                     // bar3

        // ---- P3: context partials [16][256] from LDS inp
        {
            float ax = 0.f, ay = 0.f, az = 0.f, aw = 0.f;
            #pragma unroll
            for (int i = 0; i < 8; ++i) {
                const int s = sc * 8 + i;
                const float al = sh_raw[s];
                float4 iv = *(const float4*)&sh_inp[s * 256 + e4];
                ax += al * iv.x; ay += al * iv.y; az += al * iv.z; aw += al * iv.w;
            }
            *(float4*)&red[sc * 256 + e4] = make_float4(ax, ay, az, aw);
        }
        __syncthreads();                                     // bar4
        if (t < 256) {
            float v = 0.f;
            #pragma unroll
            for (int k = 0; k < 16; ++k) v += red[k * 256 + t];
            v *= sh_misc[0];
            sh_ctx[t] = v;
            if (ts == SS - 1) hctxT[(size_t)(256 + t) * 128 + b] = v;
        }
        __syncthreads();                                     // bar5

        // ---- P3b: y_tilde partials [64][64] from register fcW
        {
            float acc[4] = {0.f, 0.f, 0.f, 0.f};
            #pragma unroll
            for (int i = 0; i < 5; ++i) {
                const int kk = kc3 * 5 + i;
                const float val = (kk < 256) ? sh_ctx[kk] : sh_y[kk - 256];
                const uint2 w = fwr[i];
                acc[0] += val * bflo(w.x); acc[1] += val * bfhi(w.x);
                acc[2] += val * bflo(w.y); acc[3] += val * bfhi(w.y);
            }
            *(float4*)&red[kc3 * 64 + o4] = make_float4(acc[0], acc[1], acc[2], acc[3]);
        }
        __syncthreads();                                     // bar6
        if (t < 64) {
            float v = fcb_reg;
            #pragma unroll 16
            for (int kc = 0; kc < 64; ++kc) v += red[kc * 64 + t];
            sh_yt[t] = v;
        }
        __syncthreads();                                     // bar7

        // ---- P4: g += Wih·yt (regs); butterfly over 8 kgroups; write gates
        {
            const float* ysrc = &sh_yt[kgb * 8];
            #pragma unroll
            for (int i = 0; i < 8; ++i) fma8(wir[i], ysrc[i], g);
            #pragma unroll
            for (int m = 8; m <= 32; m <<= 1) {
                #pragma unroll
                for (int r = 0; r < 8; ++r) g[r] += __shfl_xor(g[r], m);
            }
            if (lane < 8) {
                *(float4*)&red[wv * 64 + lane * 8]     = make_float4(g[0], g[1], g[2], g[3]);
                *(float4*)&red[wv * 64 + lane * 8 + 4] = make_float4(g[4], g[5], g[6], g[7]);
            }
        }
        __syncthreads();                                     // bar8
        if (t < 256) {
            const float gi = red[t]       + bs4[0];
            const float gf = red[256 + t] + bs4[1];
            const float gg = red[512 + t] + bs4[2];
            const float go = red[768 + t] + bs4[3];
            const float cn = fsig(gf) * sh_c[t] + fsig(gi) * ftanh(gg);
            sh_c[t] = cn;
            const float hn = fsig(go) * ftanh(cn);
            sh_h[t] = hn;
            if (ts == SS - 1) hctxT[(size_t)t * 128 + b] = hn;
        }
        __syncthreads();                                     // bar9
    }
}

// out(128 x 8192) = A(128x512, stored transposed AT[512][128]) @ W(512x8192) + bias
__global__ __launch_bounds__(256) void out_gemm(
    const float* __restrict__ AT, const float* __restrict__ W,
    const float* __restrict__ bias, float* __restrict__ out)
{
    __shared__ float Ab[64 * 132];  // [k][m]
    __shared__ float Bb[64 * 32];   // [k][n]
    const int t = threadIdx.x;
    const int nt = blockIdx.x * 32;
    const int n4 = (t & 7) * 4;
    const int m4 = (t >> 3) * 4;
    float acc[4][4];
    #pragma unroll
    for (int i = 0; i < 4; ++i)
        #pragma unroll
        for (int jj = 0; jj < 4; ++jj) acc[i][jj] = 0.f;

    for (int kc = 0; kc < 8; ++kc) {
        #pragma unroll
        for (int i = 0; i < 8; ++i) {
            const int flat4 = i * 256 + t;
            const int row = flat4 >> 5, mm4 = (flat4 & 31) * 4;
            float4 v = *(const float4*)(AT + (size_t)(kc * 64 + row) * 128 + mm4);
            *(float4*)&Ab[row * 132 + mm4] = v;
        }
        #pragma unroll
        for (int i = 0; i < 2; ++i) {
            const int fl = t + i * 256;
            const int k = fl >> 3, nn4 = (fl & 7) * 4;
            *(float4*)&Bb[k * 32 + nn4] =
                *(const float4*)(W + (size_t)(kc * 64 + k) * 8192 + nt + nn4);
        }
        __syncthreads();
        for (int k = 0; k < 64; ++k) {
            const float4 bv = *(const float4*)&Bb[k * 32 + n4];
            const float4 av = *(const float4*)&Ab[k * 132 + m4];
            acc[0][0] += av.x * bv.x; acc[0][1] += av.x * bv.y; acc[0][2] += av.x * bv.z; acc[0][3] += av.x * bv.w;
            acc[1][0] += av.y * bv.x; acc[1][1] += av.y * bv.y; acc[1][2] += av.y * bv.z; acc[1][3] += av.y * bv.w;
            acc[2][0] += av.z * bv.x; acc[2][1] += av.z * bv.y; acc[2][2] += av.z * bv.z; acc[2][3] += av.z * bv.w;
            acc[3][0] += av.w * bv.x; acc[3][1] += av.w * bv.y; acc[3][2] += av.w * bv.z; acc[3][3] += av.w * bv.w;
        }
        __syncthreads();
    }
    const float4 bb = *(const float4*)(bias + nt + n4);
    #pragma unroll
    for (int i = 0; i < 4; ++i) {
        float4 r;
        r.x = acc[i][0] + bb.x; r.y = acc[i][1] + bb.y;
        r.z = acc[i][2] + bb.z; r.w = acc[i][3] + bb.w;
        *(float4*)(out + (size_t)(m4 + i) * 8192 + nt + n4) = r;
    }
}

extern "C" void kernel_launch(void* const* d_in, const int* in_sizes, int n_in,
                              void* d_out, int out_size, void* d_ws, size_t ws_size,
                              hipStream_t stream) {
    const float* inp = (const float*)d_in[0];
    const float* yh  = (const float*)d_in[1];
    const float* h0  = (const float*)d_in[2];
    const float* c0  = (const float*)d_in[3];
    const float* W1  = (const float*)d_in[4];
    const float* b1  = (const float*)d_in[5];
    const float* w2  = (const float*)d_in[6];
    const float* b2  = (const float*)d_in[7];
    const float* Wih = (const float*)d_in[8];
    const float* Whh = (const float*)d_in[9];
    const float* bih = (const float*)d_in[10];
    const float* bhh = (const float*)d_in[11];
    const float* fcW = (const float*)d_in[12];
    const float* fcb = (const float*)d_in[13];
    const float* foW = (const float*)d_in[14];
    const float* fob = (const float*)d_in[15];

    float* hctxT = (float*)d_ws;                    // 256 KB (proven)
    unsigned short* wbf = (unsigned short*)d_out;   // 1.09 MB bf16 weights in d_out scratch
                                                    // (overwritten by out_gemm at the end)

    conv_kernel<<<dim3((WTOTAL + 255) / 256), dim3(256), 0, stream>>>(W1, Whh, Wih, fcW, wbf);
    scan_kernel<<<dim3(BB), dim3(1024), 0, stream>>>(
        inp, yh, h0, c0, W1, b1, w2, b2, bih, bhh, fcb, wbf, hctxT);
    out_gemm<<<dim3(8192 / 32), dim3(256), 0, stream>>>(hctxT, foW, fob, (float*)d_out);
}

// Round 8
// 8562.903 us; speedup vs baseline: 1.9054x; 1.9054x over previous
//
#include <hip/hip_runtime.h>

#define BB 128   // batch
#define SS 128   // seq
#define EE 256   // enc dim
#define DD 256   // lstm hidden
#define OO 64    // out dim

// bf16 weight buffer layout (ushort offsets) inside d_out scratch
#define W1_OFF   0         // 768*256   = 196608 (rows: Wh|Wc|We)
#define WHH_OFF  196608    // 256*1024  = 262144
#define WIH_OFF  458752    // 64*1024   = 65536
#define FCW_OFF  524288    // 320*64    = 20480
#define WTOTAL   544768

// red[] sub-buffers (float offsets)
#define GB  0      // gates  [1024]
#define HCB 1024   // hc     [256]  (SWZ'd)
#define CXB 1280   // ctx    [256]  (unnormalized)
#define YTB 1536   // yt     [64]

__device__ __forceinline__ float fsig(float x) { return 1.0f / (1.0f + __expf(-x)); }
__device__ __forceinline__ float ftanh(float x) {
    float t = __expf(-2.0f * fabsf(x));
    float r = (1.0f - t) / (1.0f + t);
    return copysignf(r, x);
}
// swizzle within 32-float groups (rotation by 4*(group)): conflict-free strided access
__device__ __forceinline__ int SWZ(int e) { return (e & ~31) | ((e + 4 * (e >> 5)) & 31); }
__device__ __forceinline__ float bflo(unsigned int u) { return __uint_as_float(u << 16); }
__device__ __forceinline__ float bfhi(unsigned int u) { return __uint_as_float(u & 0xffff0000u); }

__device__ __forceinline__ void fma8(const uint4 w, const float xv, float* acc) {
    acc[0] += xv * bflo(w.x); acc[1] += xv * bfhi(w.x);
    acc[2] += xv * bflo(w.y); acc[3] += xv * bfhi(w.y);
    acc[4] += xv * bflo(w.z); acc[5] += xv * bfhi(w.z);
    acc[6] += xv * bflo(w.w); acc[7] += xv * bfhi(w.w);
}

// fp32 -> bf16 (RNE) weight conversion, runs every launch (graph-safe, same work)
__global__ __launch_bounds__(256) void conv_kernel(
    const float* __restrict__ W1, const float* __restrict__ Whh,
    const float* __restrict__ Wih, const float* __restrict__ fcW,
    unsigned short* __restrict__ out)
{
    const int idx = blockIdx.x * 256 + threadIdx.x;
    float f;
    if      (idx < WHH_OFF)  f = W1[idx];
    else if (idx < WIH_OFF)  f = Whh[idx - WHH_OFF];
    else if (idx < FCW_OFF)  f = Wih[idx - WIH_OFF];
    else if (idx < WTOTAL)   f = fcW[idx - FCW_OFF];
    else return;
    unsigned int u = __float_as_uint(f);
    u = (u + 0x7fffu + ((u >> 16) & 1u)) >> 16;
    out[idx] = (unsigned short)u;
}

// One block (1024 thr, 16 waves) per batch row; whole scan block-local.
// inp lives in LDS (weights become the only per-step stream -> L2-resident).
// Cross-group reduces via ds_add_f32 atomics into small accumulators (6 barriers/step).
__global__ __launch_bounds__(1024, 4) void scan_kernel(
    const float* __restrict__ inp,   // B,S,E
    const float* __restrict__ yhist, // B,S,OO
    const float* __restrict__ h0, const float* __restrict__ c0,
    const float* __restrict__ W1f,   // fp32 W1 (only We rows used here, init)
    const float* __restrict__ b1, const float* __restrict__ w2, const float* __restrict__ b2,
    const float* __restrict__ bih, const float* __restrict__ bhh,
    const float* __restrict__ fcb,
    const unsigned short* __restrict__ wbf,  // bf16 weights (see *_OFF)
    float* __restrict__ hctxT)       // ws: [512][128] (0..255 h, 256..511 ctx)
{
    __shared__ float sh_inp[SS * EE];      // 131072 B (P3 b128 reads conflict-free)
    __shared__ float red[4096];            // 16384 B: We staging (init) / GB|HCB|CXB|YTB (scan)
    __shared__ float sh_h[DD], sh_c[DD];   // 2048
    __shared__ float sh_w2[EE];            // 1024 (SWZ'd)
    __shared__ float sh_b1[EE];            // 1024
    __shared__ float sh_bs[1024];          // 4096
    __shared__ float sh_raw[SS];           // 512  exp(scores)
    __shared__ float sh_y[OO], sh_fcb[OO]; // 512
    __shared__ float sh_misc[1];
    // total ~153 KB -> 1 block/CU

    const int b = blockIdx.x, t = threadIdx.x;
    const float* inp_b = inp + (size_t)b * SS * EE;
    const unsigned short* W1bf  = wbf + W1_OFF;
    const unsigned short* Whhbf = wbf + WHH_OFF;
    const unsigned short* Wihbf = wbf + WIH_OFF;
    const unsigned short* fcWbf = wbf + FCW_OFF;
    const float b2v = b2[0];

    // role constants (R0-proven layouts)
    const int e8  = (t & 31) * 8,  kc1 = t >> 5;   // P1: 32 kg x 16k, 8 cols uint4
    const int j8  = (t & 127) * 8, kc2 = t >> 7;   // P1b/P4: 8 kg, 8 cols uint4
    const int s_own = t >> 3,      a2  = t & 7, e0 = a2 * 32;  // P2 / enc_proj
    const int e4  = (t & 63) * 4,  sc  = t >> 6;   // P3: 16 sg x 8 s, 4 cols
    const int o4  = (t & 15) * 4,  kc3 = t >> 4;   // P3b: 64 kg x 5k, 4 cols

    // ---- stage inp -> LDS (fp32, stride 256) ----
    #pragma unroll
    for (int i = 0; i < 8; ++i) {
        const int idx = i * 1024 + t;
        const int s = idx >> 6, c4 = (idx & 63) * 4;
        *(float4*)&sh_inp[s * 256 + c4] = *(const float4*)(inp_b + (size_t)idx * 4);
    }
    if (t < 256) {
        sh_h[t] = h0[b * 256 + t]; sh_c[t] = c0[b * 256 + t];
        sh_b1[t] = b1[t];
        sh_w2[SWZ(t)] = w2[t];
    }
    if (t < 64) sh_fcb[t] = fcb[t];
    sh_bs[t] = bih[t] + bhh[t];
    __syncthreads();

    // ---- enc_proj (+b1) into registers er[32], inp from LDS, We staged in red ----
    float er[32];
    #pragma unroll
    for (int j = 0; j < 32; ++j) er[j] = 0.f;
    {
        const float* We = W1f + 512 * 256;
        for (int kc = 0; kc < 16; ++kc) {
            {   // stage We rows [kc*16,+16) x 256 -> red[0..4095]
                const int row = t >> 6, c4 = (t & 63) * 4;
                *(float4*)&red[row * 256 + c4] =
                    *(const float4*)(We + (size_t)(kc * 16 + row) * 256 + c4);
            }
            __syncthreads();
            for (int k = 0; k < 16; ++k) {
                const float xv = sh_inp[s_own * 256 + kc * 16 + k];
                #pragma unroll
                for (int j4 = 0; j4 < 8; ++j4) {
                    float4 w = *(const float4*)&red[k * 256 + e0 + j4 * 4];
                    er[j4*4+0] += xv * w.x; er[j4*4+1] += xv * w.y;
                    er[j4*4+2] += xv * w.z; er[j4*4+3] += xv * w.w;
                }
            }
            __syncthreads();
        }
        // fold b1 into er (hc accumulator then needs no bias)
        #pragma unroll
        for (int j4 = 0; j4 < 8; ++j4) {
            float4 v = *(const float4*)&sh_b1[e0 + j4 * 4];
            er[j4*4+0] += v.x; er[j4*4+1] += v.y; er[j4*4+2] += v.z; er[j4*4+3] += v.w;
        }
    }
    // zero scan accumulators (red was init staging)
    red[t] = 0.f;                                  // gates
    if (t < 256) { red[HCB + t] = 0.f; red[CXB + t] = 0.f; }
    if (t < 64)  red[YTB + t] = 0.f;
    __syncthreads();

    for (int ts = 0; ts < SS; ++ts) {
        if (t < 64) sh_y[t] = yhist[(size_t)b * SS * OO + ts * OO + t];

        // ---- P1: hc = W1·[h;c] (uint4 stream) -> atomic adds into red[HCB] (SWZ'd)
        {
            float acc[8];
            #pragma unroll
            for (int r = 0; r < 8; ++r) acc[r] = 0.f;
            #pragma unroll 4
            for (int k = kc1 * 16; k < kc1 * 16 + 16; ++k) {
                const float xv = (k < 256) ? sh_h[k] : sh_c[k - 256];
                uint4 w = *(const uint4*)(W1bf + (size_t)k * 256 + e8);
                fma8(w, xv, acc);
            }
            #pragma unroll
            for (int r = 0; r < 8; ++r) atomicAdd(&red[HCB + SWZ(e8 + r)], acc[r]);
        }
        // ---- P1b: g = Whh·h in registers (bias seeded by group 0; held to P4)
        float g[8];
        #pragma unroll
        for (int r = 0; r < 8; ++r) g[r] = (kc2 == 0) ? sh_bs[j8 + r] : 0.f;
        #pragma unroll 8
        for (int k = kc2 * 32; k < kc2 * 32 + 32; ++k) {
            const float hv = sh_h[k];
            uint4 w = *(const uint4*)(Whhbf + (size_t)k * 1024 + j8);
            fma8(w, hv, g);
        }
        __syncthreads();                                     // bar1: hc ready

        // ---- P2: scores from er + swizzled hc/w2 (conflict-free)
        {
            float acc = 0.f;
            #pragma unroll
            for (int j4 = 0; j4 < 8; ++j4) {
                const int phys = e0 + ((j4 * 4 + 4 * a2) & 31);
                float4 hc4 = *(const float4*)&red[HCB + phys];
                float4 w24 = *(const float4*)&sh_w2[phys];
                acc += ftanh(er[j4*4+0] + hc4.x) * w24.x;
                acc += ftanh(er[j4*4+1] + hc4.y) * w24.y;
                acc += ftanh(er[j4*4+2] + hc4.z) * w24.z;
                acc += ftanh(er[j4*4+3] + hc4.w) * w24.w;
            }
            acc += __shfl_xor(acc, 1);
            acc += __shfl_xor(acc, 2);
            acc += __shfl_xor(acc, 4);
            if (a2 == 0) sh_raw[s_own] = __expf(acc + b2v);  // max-free: |score| <= sum|w2| ~ 10
        }
        __syncthreads();                                     // bar2: raw ready

        // ---- P3 (ctx atomics from LDS inp) + softmax denom in parallel
        if (t < 64) {
            float v = sh_raw[t] + sh_raw[t + 64];
            #pragma unroll
            for (int m = 32; m > 0; m >>= 1) v += __shfl_xor(v, m);
            if (t == 0) sh_misc[0] = 1.0f / v;
        }
        {
            float ax = 0.f, ay = 0.f, az = 0.f, aw = 0.f;
            #pragma unroll
            for (int i = 0; i < 8; ++i) {
                const int s = sc * 8 + i;
                const float al = sh_raw[s];
                float4 iv = *(const float4*)&sh_inp[s * 256 + e4];
                ax += al * iv.x; ay += al * iv.y; az += al * iv.z; aw += al * iv.w;
            }
            atomicAdd(&red[CXB + e4],     ax);
            atomicAdd(&red[CXB + e4 + 1], ay);
            atomicAdd(&red[CXB + e4 + 2], az);
            atomicAdd(&red[CXB + e4 + 3], aw);
        }
        __syncthreads();                                     // bar3: ctx + denom ready

        // ---- P3b: y_tilde atomics (fcW stream; ctx normalized at read)
        {
            const float inv = sh_misc[0];
            float acc[4];
            #pragma unroll
            for (int i = 0; i < 4; ++i) acc[i] = (kc3 == 0) ? sh_fcb[o4 + i] : 0.f;
            #pragma unroll
            for (int kk = kc3 * 5; kk < kc3 * 5 + 5; ++kk) {
                const float val = (kk < 256) ? red[CXB + kk] * inv : sh_y[kk - 256];
                uint2 w = *(const uint2*)(fcWbf + kk * 64 + o4);
                acc[0] += val * bflo(w.x);
                acc[1] += val * bfhi(w.x);
                acc[2] += val * bflo(w.y);
                acc[3] += val * bfhi(w.y);
            }
            #pragma unroll
            for (int i = 0; i < 4; ++i) atomicAdd(&red[YTB + o4 + i], acc[i]);
        }
        __syncthreads();                                     // bar4: yt ready

        // ---- P4: g += Wih·yt (uint4 stream); atomic adds into gates
        {
            #pragma unroll
            for (int k = kc2 * 8; k < kc2 * 8 + 8; ++k) {
                const float yv = red[YTB + k];
                uint4 w = *(const uint4*)(Wihbf + (size_t)k * 1024 + j8);
                fma8(w, yv, g);
            }
            #pragma unroll
            for (int r = 0; r < 8; ++r) atomicAdd(&red[GB + j8 + r], g[r]);
        }
        __syncthreads();                                     // bar5: gates ready

        // ---- elementwise: LSTM update; zero accumulators for next step
        if (t < 256) {
            const float gi = red[GB + t],       gf = red[GB + 256 + t];
            const float gg = red[GB + 512 + t], go = red[GB + 768 + t];
            const float cn = fsig(gf) * sh_c[t] + fsig(gi) * ftanh(gg);
            sh_c[t] = cn;
            const float hn = fsig(go) * ftanh(cn);
            sh_h[t] = hn;
            if (ts == SS - 1) {
                hctxT[(size_t)t * 128 + b] = hn;
                hctxT[(size_t)(256 + t) * 128 + b] = red[CXB + t] * sh_misc[0];
            }
            red[GB + t] = 0.f; red[GB + 256 + t] = 0.f;
            red[GB + 512 + t] = 0.f; red[GB + 768 + t] = 0.f;
            red[HCB + t] = 0.f; red[CXB + t] = 0.f;
            if (t < 64) red[YTB + t] = 0.f;
        }
        __syncthreads();                                     // bar6
    }
}

// out(128 x 8192) = A(128x512, stored transposed AT[512][128]) @ W(512x8192) + bias
__global__ __launch_bounds__(256) void out_gemm(
    const float* __restrict__ AT, const float* __restrict__ W,
    const float* __restrict__ bias, float* __restrict__ out)
{
    __shared__ float Ab[64 * 132];  // [k][m]
    __shared__ float Bb[64 * 32];   // [k][n]
    const int t = threadIdx.x;
    const int nt = blockIdx.x * 32;
    const int n4 = (t & 7) * 4;
    const int m4 = (t >> 3) * 4;
    float acc[4][4];
    #pragma unroll
    for (int i = 0; i < 4; ++i)
        #pragma unroll
        for (int jj = 0; jj < 4; ++jj) acc[i][jj] = 0.f;

    for (int kc = 0; kc < 8; ++kc) {
        #pragma unroll
        for (int i = 0; i < 8; ++i) {
            const int flat4 = i * 256 + t;
            const int row = flat4 >> 5, mm4 = (flat4 & 31) * 4;
            float4 v = *(const float4*)(AT + (size_t)(kc * 64 + row) * 128 + mm4);
            *(float4*)&Ab[row * 132 + mm4] = v;
        }
        #pragma unroll
        for (int i = 0; i < 2; ++i) {
            const int fl = t + i * 256;
            const int k = fl >> 3, nn4 = (fl & 7) * 4;
            *(float4*)&Bb[k * 32 + nn4] =
                *(const float4*)(W + (size_t)(kc * 64 + k) * 8192 + nt + nn4);
        }
        __syncthreads();
        for (int k = 0; k < 64; ++k) {
            const float4 bv = *(const float4*)&Bb[k * 32 + n4];
            const float4 av = *(const float4*)&Ab[k * 132 + m4];
            acc[0][0] += av.x * bv.x; acc[0][1] += av.x * bv.y; acc[0][2] += av.x * bv.z; acc[0][3] += av.x * bv.w;
            acc[1][0] += av.y * bv.x; acc[1][1] += av.y * bv.y; acc[1][2] += av.y * bv.z; acc[1][3] += av.y * bv.w;
            acc[2][0] += av.z * bv.x; acc[2][1] += av.z * bv.y; acc[2][2] += av.z * bv.z; acc[2][3] += av.z * bv.w;
            acc[3][0] += av.w * bv.x; acc[3][1] += av.w * bv.y; acc[3][2] += av.w * bv.z; acc[3][3] += av.w * bv.w;
        }
        __syncthreads();
    }
    const float4 bb = *(const float4*)(bias + nt + n4);
    #pragma unroll
    for (int i = 0; i < 4; ++i) {
        float4 r;
        r.x = acc[i][0] + bb.x; r.y = acc[i][1] + bb.y;
        r.z = acc[i][2] + bb.z; r.w = acc[i][3] + bb.w;
        *(float4*)(out + (size_t)(m4 + i) * 8192 + nt + n4) = r;
    }
}

extern "C" void kernel_launch(void* const* d_in, const int* in_sizes, int n_in,
                              void* d_out, int out_size, void* d_ws, size_t ws_size,
                              hipStream_t stream) {
    const float* inp = (const float*)d_in[0];
    const float* yh  = (const float*)d_in[1];
    const float* h0  = (const float*)d_in[2];
    const float* c0  = (const float*)d_in[3];
    const float* W1  = (const float*)d_in[4];
    const float* b1  = (const float*)d_in[5];
    const float* w2  = (const float*)d_in[6];
    const float* b2  = (const float*)d_in[7];
    const float* Wih = (const float*)d_in[8];
    const float* Whh = (const float*)d_in[9];
    const float* bih = (const float*)d_in[10];
    const float* bhh = (const float*)d_in[11];
    const float* fcW = (const float*)d_in[12];
    const float* fcb = (const float*)d_in[13];
    const float* foW = (const float*)d_in[14];
    const float* fob = (const float*)d_in[15];

    float* hctxT = (float*)d_ws;                    // 256 KB (proven)
    unsigned short* wbf = (unsigned short*)d_out;   // 1.09 MB bf16 weights in d_out scratch
                                                    // (overwritten by out_gemm at the end)

    conv_kernel<<<dim3((WTOTAL + 255) / 256), dim3(256), 0, stream>>>(W1, Whh, Wih, fcW, wbf);
    scan_kernel<<<dim3(BB), dim3(1024), 0, stream>>>(
        inp, yh, h0, c0, W1, b1, w2, b2, bih, bhh, fcb, wbf, hctxT);
    out_gemm<<<dim3(8192 / 32), dim3(256), 0, stream>>>(hctxT, foW, fob, (float*)d_out);
}